// Round 18
// baseline (67.746 us; speedup 1.0000x reference)
//
#include <hip/hip_runtime.h>

#define CUT0 20000
#define CUT1 60000
#define D    1024
#define D1   256
#define D2   64
#define NTOK 32768

typedef __bf16  bf16x4 __attribute__((ext_vector_type(4)));
typedef __bf16  bf16x8 __attribute__((ext_vector_type(8)));
typedef float   f32x4  __attribute__((ext_vector_type(4)));

// ws layout:
//   int      cnt[64]
//   unsigned list0/1/2[NTOK]         packed (tok<<17)|local_idx
//   __bf16   w1b[D*D1], w2b[D*D2]    ([d][k] layout, MFMA A-operand rows)

// grid: [0,128) token classify; [128,288) vectorized w-cast (8 elem/thread)
__global__ __launch_bounds__(256) void k_classify(
        const int* __restrict__ ids,
        const float* __restrict__ w1,
        const float* __restrict__ w2,
        int* cnt, unsigned* list0, unsigned* list1, unsigned* list2,
        __bf16* __restrict__ w1b, __bf16* __restrict__ w2b) {
    int bid = blockIdx.x, tid = threadIdx.x;
    if (bid < NTOK / 256) {
        unsigned t = bid * 256 + tid;
        int id = ids[t];
        int lane = tid & 63;
        unsigned long long lanebit = 1ull << lane;
        int c = (id < CUT0) ? 0 : (id < CUT1 ? 1 : 2);
        {
            unsigned long long m = __ballot(c == 0);
            if (m) {
                int base = 0;
                if (lane == 0) base = atomicAdd(cnt + 0, __popcll(m));
                base = __shfl(base, 0);
                if (c == 0) list0[base + __popcll(m & (lanebit - 1))] = (t << 17) | (unsigned)id;
            }
        }
        {
            unsigned long long m = __ballot(c == 1);
            if (m) {
                int base = 0;
                if (lane == 0) base = atomicAdd(cnt + 1, __popcll(m));
                base = __shfl(base, 0);
                if (c == 1) list1[base + __popcll(m & (lanebit - 1))] = (t << 17) | (unsigned)(id - CUT0);
            }
        }
        {
            unsigned long long m = __ballot(c == 2);
            if (m) {
                int base = 0;
                if (lane == 0) base = atomicAdd(cnt + 2, __popcll(m));
                base = __shfl(base, 0);
                if (c == 2) list2[base + __popcll(m & (lanebit - 1))] = (t << 17) | (unsigned)(id - CUT1);
            }
        }
    } else {
        // vectorized cast: 8 consecutive elements per thread, bf16x8 store.
        int i = (bid - NTOK / 256) * 2048 + tid * 8;
        const float* src;
        __bf16* dst;
        if (i < D * D1) { src = w1 + i;            dst = w1b + i; }
        else            { src = w2 + (i - D * D1); dst = w2b + (i - D * D1); }
        float4 x = *(const float4*)src;
        float4 y = *(const float4*)(src + 4);
        bf16x8 v = { (__bf16)x.x, (__bf16)x.y, (__bf16)x.z, (__bf16)x.w,
                     (__bf16)y.x, (__bf16)y.y, (__bf16)y.z, (__bf16)y.w };
        *(bf16x8*)dst = v;
    }
}

// Block = 512 thr (8 waves) = 64 tok x 512 d; wave tile 64 tok x 64 d, acc[4][4].
// Fragments (verified rounds 4-16):
//   A: lane holds w d-row wdb+t*16+(lane&15), k=(lane>>4)*8+j (+32/ks)
//   B: lane holds token col c*16+(lane&15), same k slots (LDS, chunk-XOR swz)
//   C/D: col=lane&15 (token), row=(lane>>4)*4+r (d)
// Epilogue LDS transpose: each store instr = 4 tokens x 256B contiguous.
// R18: nontemporal stores via f32x4 (ext_vector_type — builtin-compatible).
template<int K>
__device__ __forceinline__ void gemm_block(
        const float* __restrict__ emb, const __bf16* __restrict__ wb,
        const float* __restrict__ bias, float* __restrict__ out,
        const unsigned* __restrict__ list, int n, int base, int sd,
        int tid, __bf16* Es, unsigned* plist) {
    constexpr int KS  = K / 32;
    constexpr int SWZ = (K / 8 >= 16) ? 15 : 7;   // XOR mask on 16B-chunk idx

    // gather 64 rows x K floats -> bf16 LDS (swizzled). 8 threads/row.
    {
        int r = tid >> 3, q = tid & 7;
        int li = base + r; if (li >= n) li = n - 1;
        unsigned p = list[li];
        if (q == 0) plist[r] = p;     // consumed in epilogue (2 barriers later)
        const float* src = emb + (size_t)(p & 0x1FFFFu) * K + q * (K / 8);
#pragma unroll
        for (int f = 0; f < K / 32; f++) {
            float4 x = ((const float4*)src)[f];
            bf16x4 v = { (__bf16)x.x, (__bf16)x.y, (__bf16)x.z, (__bf16)x.w };
            int k = q * (K / 8) + f * 4;
            int chunk = (k >> 3) ^ (r & SWZ);
            *(bf16x4*)(Es + r * K + chunk * 8 + (k & 7)) = v;
        }
    }
    __syncthreads();

    int lane = tid & 63, wv = tid >> 6;
    int row16 = lane & 15, kg = lane >> 4;
    int wdb = sd + wv * 64;

    f32x4 acc[4][4];
#pragma unroll
    for (int t = 0; t < 4; t++)
#pragma unroll
        for (int c = 0; c < 4; c++) acc[t][c] = (f32x4){0.f, 0.f, 0.f, 0.f};

#pragma unroll
    for (int ks = 0; ks < KS; ks++) {
        bf16x8 b[4];
#pragma unroll
        for (int c = 0; c < 4; c++) {
            int rr = c * 16 + row16;
            int ch = (kg + ks * 4) ^ (rr & SWZ);
            b[c] = *(const bf16x8*)(Es + rr * K + ch * 8);
        }
#pragma unroll
        for (int t = 0; t < 4; t++) {
            bf16x8 a = *(const bf16x8*)(wb + (size_t)(wdb + t * 16 + row16) * K + kg * 8 + ks * 32);
#pragma unroll
            for (int c = 0; c < 4; c++)
                acc[t][c] = __builtin_amdgcn_mfma_f32_16x16x32_bf16(a, b[c], acc[t][c], 0, 0, 0);
        }
    }

    __syncthreads();   // all waves done reading Es -> reuse as f32 slabs

    // epilogue: per-wave private 4KB slab (wave-lockstep, in-order DS ops).
    float* slab = (float*)Es + wv * 1024;
#pragma unroll
    for (int c = 0; c < 4; c++) {
#pragma unroll
        for (int t = 0; t < 4; t++) {
            float4 bs = *(const float4*)(bias + wdb + t * 16 + kg * 4);
            f32x4 v = acc[t][c];
            v[0] += bs.x; v[1] += bs.y; v[2] += bs.z; v[3] += bs.w;
            int phys = (((t ^ (row16 >> 2)) & 3) << 2) | ((kg ^ row16) & 3);
            *(f32x4*)(slab + row16 * 64 + phys * 4) = v;
        }
#pragma unroll
        for (int i = 0; i < 4; i++) {
            int tk = i * 4 + (lane >> 4);         // token within quarter
            int lc = lane & 15;                   // logical chunk (d = lc*4)
            int phys = ((((lc >> 2) ^ (tk >> 2)) & 3) << 2) | ((lc ^ tk) & 3);
            f32x4 v = *(const f32x4*)(slab + tk * 64 + phys * 4);
            int lt = c * 16 + tk;                 // local plist index
            if (base + lt < n) {
                unsigned p = plist[lt];
                __builtin_nontemporal_store(v,
                    (f32x4*)(out + (size_t)(p >> 17) * D + wdb + lc * 4));
            }
        }
    }
}

// grid: [0,256) c0 copy role (FIRST); [256,1280) c1; [1280,2304) c2. 512 thr.
__global__ __launch_bounds__(512, 4) void k_work(
        const float* __restrict__ emb0,
        const float* __restrict__ emb1,
        const float* __restrict__ emb2,
        const float* __restrict__ b1,
        const float* __restrict__ b2,
        float* __restrict__ out,
        const int* __restrict__ cnt,
        const unsigned* __restrict__ list0,
        const unsigned* __restrict__ list1,
        const unsigned* __restrict__ list2,
        const __bf16* __restrict__ w1b,
        const __bf16* __restrict__ w2b) {
    __shared__ __bf16 Es[64 * 256];    // 32 KB (gather tile, then f32 slabs)
    __shared__ unsigned plist[64];

    int bid = blockIdx.x, tid = threadIdx.x;

    if (bid < 256) {
        // c0 copy: 2 rows per iter, 256 thr/row, next-entry prefetch, nt I/O
        int n0 = cnt[0];
        int f = tid & 255;
        int r = bid * 2 + (tid >> 8);
        if (r >= n0) return;
        unsigned p = list0[r];
        for (;;) {
            int rn = r + 512;
            unsigned pn = (rn < n0) ? list0[rn] : 0u;
            const f32x4* src = (const f32x4*)(emb0 + (size_t)(p & 0x1FFFFu) * D);
            f32x4* dst = (f32x4*)(out + (size_t)(p >> 17) * D);
            f32x4 v = __builtin_nontemporal_load(src + f);
            __builtin_nontemporal_store(v, dst + f);
            if (rn >= n0) break;
            r = rn; p = pn;
        }
        return;
    }

    if (bid < 1280) {
        int e = bid - 256;
        int n = cnt[1];
        int base = (e >> 1) * 64;
        if (base >= n) return;
        gemm_block<D1>(emb1, w1b, b1, out, list1, n, base, (e & 1) * 512, tid, Es, plist);
    } else {
        int e = bid - 1280;
        int n = cnt[2];
        int base = (e >> 1) * 64;
        if (base >= n) return;
        gemm_block<D2>(emb2, w2b, b2, out, list2, n, base, (e & 1) * 512, tid, Es, plist);
    }
}

extern "C" void kernel_launch(void* const* d_in, const int* in_sizes, int n_in,
                              void* d_out, int out_size, void* d_ws, size_t ws_size,
                              hipStream_t stream) {
    const int*   ids  = (const int*)d_in[0];
    const float* emb0 = (const float*)d_in[1];
    const float* emb1 = (const float*)d_in[2];
    const float* emb2 = (const float*)d_in[3];
    const float* w1   = (const float*)d_in[4];
    const float* b1   = (const float*)d_in[5];
    const float* w2   = (const float*)d_in[6];
    const float* b2   = (const float*)d_in[7];
    float* out = (float*)d_out;

    int* cnt        = (int*)d_ws;
    unsigned* list0 = (unsigned*)((char*)d_ws + 256);
    unsigned* list1 = list0 + NTOK;
    unsigned* list2 = list1 + NTOK;
    __bf16* w1b     = (__bf16*)(list2 + NTOK);
    __bf16* w2b     = w1b + (size_t)D * D1;

    (void)hipMemsetAsync(cnt, 0, 3 * sizeof(int), stream);
    // 128 token blocks + 160 vectorized cast blocks
    hipLaunchKernelGGL(k_classify, dim3(NTOK / 256 + 160), dim3(256), 0, stream,
                       ids, w1, w2, cnt, list0, list1, list2, w1b, w2b);
    hipLaunchKernelGGL(k_work, dim3(2304), dim3(512), 0, stream,
                       emb0, emb1, emb2, b1, b2, out, cnt,
                       list0, list1, list2, w1b, w2b);
}

// Round 19
// 64.330 us; speedup vs baseline: 1.0531x; 1.0531x over previous
//
#include <hip/hip_runtime.h>

#define CUT0 20000
#define CUT1 60000
#define D    1024
#define D1   256
#define D2   64
#define NTOK 32768

typedef __bf16  bf16x4 __attribute__((ext_vector_type(4)));
typedef __bf16  bf16x8 __attribute__((ext_vector_type(8)));
typedef float   f32x4  __attribute__((ext_vector_type(4)));

// ws layout:
//   int      cnt[64]
//   unsigned list0/1/2[NTOK]         packed (tok<<17)|local_idx
//   __bf16   w1b[D*D1], w2b[D*D2]    ([d][k] layout, MFMA A-operand rows)

// grid: [0,128) token classify; [128,288) vectorized w-cast (8 elem/thread)
__global__ __launch_bounds__(256) void k_classify(
        const int* __restrict__ ids,
        const float* __restrict__ w1,
        const float* __restrict__ w2,
        int* cnt, unsigned* list0, unsigned* list1, unsigned* list2,
        __bf16* __restrict__ w1b, __bf16* __restrict__ w2b) {
    int bid = blockIdx.x, tid = threadIdx.x;
    if (bid < NTOK / 256) {
        unsigned t = bid * 256 + tid;
        int id = ids[t];
        int lane = tid & 63;
        unsigned long long lanebit = 1ull << lane;
        int c = (id < CUT0) ? 0 : (id < CUT1 ? 1 : 2);
        {
            unsigned long long m = __ballot(c == 0);
            if (m) {
                int base = 0;
                if (lane == 0) base = atomicAdd(cnt + 0, __popcll(m));
                base = __shfl(base, 0);
                if (c == 0) list0[base + __popcll(m & (lanebit - 1))] = (t << 17) | (unsigned)id;
            }
        }
        {
            unsigned long long m = __ballot(c == 1);
            if (m) {
                int base = 0;
                if (lane == 0) base = atomicAdd(cnt + 1, __popcll(m));
                base = __shfl(base, 0);
                if (c == 1) list1[base + __popcll(m & (lanebit - 1))] = (t << 17) | (unsigned)(id - CUT0);
            }
        }
        {
            unsigned long long m = __ballot(c == 2);
            if (m) {
                int base = 0;
                if (lane == 0) base = atomicAdd(cnt + 2, __popcll(m));
                base = __shfl(base, 0);
                if (c == 2) list2[base + __popcll(m & (lanebit - 1))] = (t << 17) | (unsigned)(id - CUT1);
            }
        }
    } else {
        // vectorized cast: 8 consecutive elements per thread, bf16x8 store.
        int i = (bid - NTOK / 256) * 2048 + tid * 8;
        const float* src;
        __bf16* dst;
        if (i < D * D1) { src = w1 + i;            dst = w1b + i; }
        else            { src = w2 + (i - D * D1); dst = w2b + (i - D * D1); }
        float4 x = *(const float4*)src;
        float4 y = *(const float4*)(src + 4);
        bf16x8 v = { (__bf16)x.x, (__bf16)x.y, (__bf16)x.z, (__bf16)x.w,
                     (__bf16)y.x, (__bf16)y.y, (__bf16)y.z, (__bf16)y.w };
        *(bf16x8*)dst = v;
    }
}

// Block = 512 thr (8 waves) = 64 tok x 512 d; wave tile 64 tok x 64 d, acc[4][4].
// Fragments (verified rounds 4-18):
//   A: lane holds w d-row wdb+t*16+(lane&15), k=(lane>>4)*8+j (+32/ks)
//   B: lane holds token col c*16+(lane&15), same k slots (LDS, chunk-XOR swz)
//   C/D: col=lane&15 (token), row=(lane>>4)*4+r (d)
// Epilogue LDS transpose: each store instr = 4 tokens x 256B contiguous.
template<int K>
__device__ __forceinline__ void gemm_block(
        const float* __restrict__ emb, const __bf16* __restrict__ wb,
        const float* __restrict__ bias, float* __restrict__ out,
        const unsigned* __restrict__ list, int n, int base, int sd,
        int tid, __bf16* Es, unsigned* plist) {
    constexpr int KS  = K / 32;
    constexpr int SWZ = (K / 8 >= 16) ? 15 : 7;   // XOR mask on 16B-chunk idx

    // gather 64 rows x K floats -> bf16 LDS (swizzled). 8 threads/row.
    {
        int r = tid >> 3, q = tid & 7;
        int li = base + r; if (li >= n) li = n - 1;
        unsigned p = list[li];
        if (q == 0) plist[r] = p;     // consumed in epilogue (2 barriers later)
        const float* src = emb + (size_t)(p & 0x1FFFFu) * K + q * (K / 8);
#pragma unroll
        for (int f = 0; f < K / 32; f++) {
            float4 x = ((const float4*)src)[f];
            bf16x4 v = { (__bf16)x.x, (__bf16)x.y, (__bf16)x.z, (__bf16)x.w };
            int k = q * (K / 8) + f * 4;
            int chunk = (k >> 3) ^ (r & SWZ);
            *(bf16x4*)(Es + r * K + chunk * 8 + (k & 7)) = v;
        }
    }
    __syncthreads();

    int lane = tid & 63, wv = tid >> 6;
    int row16 = lane & 15, kg = lane >> 4;
    int wdb = sd + wv * 64;

    f32x4 acc[4][4];
#pragma unroll
    for (int t = 0; t < 4; t++)
#pragma unroll
        for (int c = 0; c < 4; c++) acc[t][c] = (f32x4){0.f, 0.f, 0.f, 0.f};

#pragma unroll
    for (int ks = 0; ks < KS; ks++) {
        bf16x8 b[4];
#pragma unroll
        for (int c = 0; c < 4; c++) {
            int rr = c * 16 + row16;
            int ch = (kg + ks * 4) ^ (rr & SWZ);
            b[c] = *(const bf16x8*)(Es + rr * K + ch * 8);
        }
#pragma unroll
        for (int t = 0; t < 4; t++) {
            bf16x8 a = *(const bf16x8*)(wb + (size_t)(wdb + t * 16 + row16) * K + kg * 8 + ks * 32);
#pragma unroll
            for (int c = 0; c < 4; c++)
                acc[t][c] = __builtin_amdgcn_mfma_f32_16x16x32_bf16(a, b[c], acc[t][c], 0, 0, 0);
        }
    }

    __syncthreads();   // all waves done reading Es -> reuse as f32 slabs

    // epilogue: per-wave private 4KB slab (wave-lockstep, in-order DS ops).
    // slab layout: [token 0..15][16 chunks of 4 floats], chunk XOR-swizzled.
    float* slab = (float*)Es + wv * 1024;
#pragma unroll
    for (int c = 0; c < 4; c++) {
        // write: 16 tokens (c*16+row16) x 64 d, bias added
#pragma unroll
        for (int t = 0; t < 4; t++) {
            float4 bs = *(const float4*)(bias + wdb + t * 16 + kg * 4);
            f32x4 v = acc[t][c];
            v[0] += bs.x; v[1] += bs.y; v[2] += bs.z; v[3] += bs.w;
            int phys = (((t ^ (row16 >> 2)) & 3) << 2) | ((kg ^ row16) & 3);
            *(f32x4*)(slab + row16 * 64 + phys * 4) = v;
        }
        // read back token-major + store: 4 tokens x 256B contiguous per instr
#pragma unroll
        for (int i = 0; i < 4; i++) {
            int tk = i * 4 + (lane >> 4);         // token within quarter
            int lc = lane & 15;                   // logical chunk (d = lc*4)
            int phys = ((((lc >> 2) ^ (tk >> 2)) & 3) << 2) | ((lc ^ tk) & 3);
            f32x4 v = *(const f32x4*)(slab + tk * 64 + phys * 4);
            int lt = c * 16 + tk;                 // local plist index
            if (base + lt < n) {
                unsigned p = plist[lt];
                float4 o = { v[0], v[1], v[2], v[3] };
                *(float4*)(out + (size_t)(p >> 17) * D + wdb + lc * 4) = o;
            }
        }
    }
}

// grid: [0,256) c0 copy role (FIRST); [256,1280) c1; [1280,2304) c2. 512 thr.
__global__ __launch_bounds__(512, 4) void k_work(
        const float* __restrict__ emb0,
        const float* __restrict__ emb1,
        const float* __restrict__ emb2,
        const float* __restrict__ b1,
        const float* __restrict__ b2,
        float* __restrict__ out,
        const int* __restrict__ cnt,
        const unsigned* __restrict__ list0,
        const unsigned* __restrict__ list1,
        const unsigned* __restrict__ list2,
        const __bf16* __restrict__ w1b,
        const __bf16* __restrict__ w2b) {
    __shared__ __bf16 Es[64 * 256];    // 32 KB (gather tile, then f32 slabs)
    __shared__ unsigned plist[64];

    int bid = blockIdx.x, tid = threadIdx.x;

    if (bid < 256) {
        // c0 copy: 2 rows per iter, 256 thr/row, next-entry prefetch
        int n0 = cnt[0];
        int f = tid & 255;
        int r = bid * 2 + (tid >> 8);
        if (r >= n0) return;
        unsigned p = list0[r];
        for (;;) {
            int rn = r + 512;
            unsigned pn = (rn < n0) ? list0[rn] : 0u;
            const float4* src = (const float4*)(emb0 + (size_t)(p & 0x1FFFFu) * D);
            float4* dst = (float4*)(out + (size_t)(p >> 17) * D);
            dst[f] = src[f];
            if (rn >= n0) break;
            r = rn; p = pn;
        }
        return;
    }

    if (bid < 1280) {
        int e = bid - 256;
        int n = cnt[1];
        int base = (e >> 1) * 64;
        if (base >= n) return;
        gemm_block<D1>(emb1, w1b, b1, out, list1, n, base, (e & 1) * 512, tid, Es, plist);
    } else {
        int e = bid - 1280;
        int n = cnt[2];
        int base = (e >> 1) * 64;
        if (base >= n) return;
        gemm_block<D2>(emb2, w2b, b2, out, list2, n, base, (e & 1) * 512, tid, Es, plist);
    }
}

extern "C" void kernel_launch(void* const* d_in, const int* in_sizes, int n_in,
                              void* d_out, int out_size, void* d_ws, size_t ws_size,
                              hipStream_t stream) {
    const int*   ids  = (const int*)d_in[0];
    const float* emb0 = (const float*)d_in[1];
    const float* emb1 = (const float*)d_in[2];
    const float* emb2 = (const float*)d_in[3];
    const float* w1   = (const float*)d_in[4];
    const float* b1   = (const float*)d_in[5];
    const float* w2   = (const float*)d_in[6];
    const float* b2   = (const float*)d_in[7];
    float* out = (float*)d_out;

    int* cnt        = (int*)d_ws;
    unsigned* list0 = (unsigned*)((char*)d_ws + 256);
    unsigned* list1 = list0 + NTOK;
    unsigned* list2 = list1 + NTOK;
    __bf16* w1b     = (__bf16*)(list2 + NTOK);
    __bf16* w2b     = w1b + (size_t)D * D1;

    (void)hipMemsetAsync(cnt, 0, 3 * sizeof(int), stream);
    // 128 token blocks + 160 vectorized cast blocks
    hipLaunchKernelGGL(k_classify, dim3(NTOK / 256 + 160), dim3(256), 0, stream,
                       ids, w1, w2, cnt, list0, list1, list2, w1b, w2b);
    hipLaunchKernelGGL(k_work, dim3(2304), dim3(512), 0, stream,
                       emb0, emb1, emb2, b1, b2, out, cnt,
                       list0, list1, list2, w1b, w2b);
}